// Round 1
// baseline (101.863 us; speedup 1.0000x reference)
//
#include <hip/hip_runtime.h>
#include <math.h>

#define IOTA_F (1.0f / 137.0f)
#define PHI_F  0.618033988749894f

__device__ __forceinline__ float sigm(float x) { return 1.0f / (1.0f + expf(-x)); }

__device__ __forceinline__ float nan2num(float v) {
    if (isnan(v)) return IOTA_F;
    if (isinf(v)) return v > 0.0f ? 1.0f : IOTA_F;
    return v;
}

// ---------------------------------------------------------------------------
// Kernel 1: instance_norm(5) -> rfft(5) -> re*im -> sigmoid -> softmax(3)
//           -> bilinear(3x3 -> 9) -> mask(u1) -> B1[9][2048]
// ---------------------------------------------------------------------------
__global__ void k_pre(const float* __restrict__ signal,  // [5][2048]
                      const float* __restrict__ u1,      // [9][2048]
                      const float* __restrict__ bilW,    // [9][3][3]
                      const float* __restrict__ bilb,    // [9]
                      float* __restrict__ B1)            // [9][2048]
{
    int s = blockIdx.x * blockDim.x + threadIdx.x;
    if (s >= 2048) return;

    float x0 = signal[0 * 2048 + s];
    float x1 = signal[1 * 2048 + s];
    float x2 = signal[2 * 2048 + s];
    float x3 = signal[3 * 2048 + s];
    float x4 = signal[4 * 2048 + s];

    float mean = (x0 + x1 + x2 + x3 + x4) * 0.2f;
    float d0 = x0 - mean, d1 = x1 - mean, d2 = x2 - mean, d3 = x3 - mean, d4 = x4 - mean;
    float var = (d0 * d0 + d1 * d1 + d2 * d2 + d3 * d3 + d4 * d4) * 0.2f;
    float r = 1.0f / sqrtf(var + 1e-9f);
    d0 *= r; d1 *= r; d2 *= r; d3 *= r; d4 *= r;

    // 5-point rfft (numpy convention: X[k] = sum x[n] exp(-2*pi*i*k*n/5))
    const float c1 = 0.30901699437494742f;   // cos(2pi/5)
    const float c2 = -0.80901699437494745f;  // cos(4pi/5)
    const float s1 = 0.95105651629515357f;   // sin(2pi/5)
    const float s2 = 0.58778525229247314f;   // sin(4pi/5)

    float re1 = d0 + c1 * (d1 + d4) + c2 * (d2 + d3);
    float im1 = -(s1 * (d1 - d4) + s2 * (d2 - d3));
    float re2 = d0 + c2 * (d1 + d4) + c1 * (d2 + d3);
    float im2 = -s2 * (d1 - d4) + s1 * (d2 - d3);

    float p1 = nan2num(re1 * im1);
    float p2 = nan2num(re2 * im2);
    // k=0: imag part is exactly 0 -> product 0 -> sigmoid = 0.5
    float g0 = 0.5f;
    float g1 = sigm(p1);
    float g2 = sigm(p2);

    float mx = fmaxf(g0, fmaxf(g1, g2));
    float e0 = expf(g0 - mx), e1 = expf(g1 - mx), e2 = expf(g2 - mx);
    float inv = 1.0f / (e0 + e1 + e2);
    float w[3] = { e0 * inv, e1 * inv, e2 * inv };

    #pragma unroll
    for (int kk = 0; kk < 9; ++kk) {
        float acc = bilb[kk];
        #pragma unroll
        for (int i = 0; i < 3; ++i)
            #pragma unroll
            for (int j = 0; j < 3; ++j)
                acc += w[i] * bilW[kk * 9 + i * 3 + j] * w[j];
        float mask = (u1[kk * 2048 + s] < PHI_F) ? 1.0f : 0.0f;
        B1[kk * 2048 + s] = IOTA_F + acc * mask;
    }
}

// ---------------------------------------------------------------------------
// Kernel 2: Out[m][jj] = dot(B[m][:], W[row(jj)][:]) + bias1[row] (+ bias2[row])
// 16 lanes per weight row, 4 rows per wave. GATEMAP skips dead f-gate rows:
//   jj in [0,2048)    -> j = jj          (i gates)
//   jj in [2048,4096) -> j = jj + 2048   (g gates, rows 4096..6143)
//   jj in [4096,6144) -> j = jj + 2048   (o gates, rows 6144..8191)
// ---------------------------------------------------------------------------
template <bool GATEMAP>
__global__ __launch_bounds__(256) void k_gemv9(
    const float* __restrict__ B,     // [9][2048]
    const float* __restrict__ W,     // [nrows][2048]
    const float* __restrict__ bias1,
    const float* __restrict__ bias2,
    float* __restrict__ Out,         // [9][nvrows]
    int nvrows)
{
    const int tid  = threadIdx.x;
    const int lane = tid & 63;
    const int grp  = lane >> 4;   // 0..3
    const int li   = lane & 15;   // 0..15
    const int wid  = (blockIdx.x * blockDim.x + tid) >> 6;
    const int jj   = wid * 4 + grp;
    if (jj >= nvrows) return;

    int j = jj;
    if (GATEMAP && jj >= 2048) j = jj + 2048;

    const float4* __restrict__ W4 = reinterpret_cast<const float4*>(W) + (size_t)j * 512;
    const float4* __restrict__ B4 = reinterpret_cast<const float4*>(B);

    float acc[9];
    #pragma unroll
    for (int m = 0; m < 9; ++m) acc[m] = 0.0f;

    #pragma unroll 2
    for (int it = 0; it < 32; ++it) {
        const int idx = it * 16 + li;
        float4 wv = W4[idx];
        #pragma unroll
        for (int m = 0; m < 9; ++m) {
            float4 bv = B4[m * 512 + idx];
            acc[m] = fmaf(wv.x, bv.x, acc[m]);
            acc[m] = fmaf(wv.y, bv.y, acc[m]);
            acc[m] = fmaf(wv.z, bv.z, acc[m]);
            acc[m] = fmaf(wv.w, bv.w, acc[m]);
        }
    }

    // reduce within each 16-lane group
    #pragma unroll
    for (int m = 0; m < 9; ++m) {
        float v = acc[m];
        v += __shfl_xor(v, 1);
        v += __shfl_xor(v, 2);
        v += __shfl_xor(v, 4);
        v += __shfl_xor(v, 8);
        acc[m] = v;
    }

    if (li == 0) {
        float bias = bias1 ? bias1[j] : 0.0f;
        if (bias2) bias += bias2[j];
        #pragma unroll
        for (int m = 0; m < 9; ++m)
            Out[(size_t)m * nvrows + jj] = acc[m] + bias;
    }
}

// ---------------------------------------------------------------------------
// Kernel 3: LSTM nonlinearity + optional mask.
//   h = sigmoid(o) * tanh(sigmoid(i) * tanh(g));  (c0 = 0 -> f gate dead)
//   if mask: out = IOTA + h * (u < PHI)
// ---------------------------------------------------------------------------
__global__ void k_combine(const float* __restrict__ G,  // [9][6144] (i,g,o)
                          const float* __restrict__ u,  // [9][2048] or nullptr
                          float* __restrict__ Bout)     // [9][2048]
{
    int idx = blockIdx.x * blockDim.x + threadIdx.x;
    if (idx >= 9 * 2048) return;
    int m = idx >> 11;
    int q = idx & 2047;
    const float* Gm = G + (size_t)m * 6144;
    float iv = Gm[q];
    float gv = Gm[2048 + q];
    float ov = Gm[4096 + q];
    float c = sigm(iv) * tanhf(gv);
    float h = sigm(ov) * tanhf(c);
    if (u) h = IOTA_F + h * ((u[idx] < PHI_F) ? 1.0f : 0.0f);
    Bout[idx] = h;
}

// ---------------------------------------------------------------------------
// Kernel 4: per sample a: t[s] = sum_{k=0..8} Z[a*18432 + s*9 + k];
//           instance_norm over s; softmax over s.
// ---------------------------------------------------------------------------
__device__ __forceinline__ float block_reduce(float v, float* red, int tid, int op) {
    #pragma unroll
    for (int off = 32; off > 0; off >>= 1) {
        float o = __shfl_xor(v, off);
        v = op ? fmaxf(v, o) : (v + o);
    }
    __syncthreads();  // protect red from previous round
    if ((tid & 63) == 0) red[tid >> 6] = v;
    __syncthreads();
    float r = red[0];
    #pragma unroll
    for (int w = 1; w < 8; ++w) r = op ? fmaxf(r, red[w]) : (r + red[w]);
    return r;
}

__global__ void k_final(const float* __restrict__ Z,  // [92160] flat
                        float* __restrict__ out)      // [5][2048]
{
    __shared__ float t[2048];
    __shared__ float red[8];
    const int a = blockIdx.x;
    const int tid = threadIdx.x;  // 512 threads

    for (int s = tid; s < 2048; s += 512) {
        const float* zp = Z + a * 18432 + s * 9;
        float acc = 0.0f;
        #pragma unroll
        for (int k = 0; k < 9; ++k) acc += zp[k];
        t[s] = acc;
    }
    __syncthreads();

    float l0 = t[tid], l1 = t[tid + 512], l2 = t[tid + 1024], l3 = t[tid + 1536];

    float ssum = block_reduce(l0 + l1 + l2 + l3, red, tid, 0);
    float mean = ssum * (1.0f / 2048.0f);
    float e0 = l0 - mean, e1 = l1 - mean, e2 = l2 - mean, e3 = l3 - mean;
    float vsum = block_reduce(e0 * e0 + e1 * e1 + e2 * e2 + e3 * e3, red, tid, 0);
    float rstd = 1.0f / sqrtf(vsum * (1.0f / 2048.0f) + 1e-9f);
    float xn0 = e0 * rstd, xn1 = e1 * rstd, xn2 = e2 * rstd, xn3 = e3 * rstd;

    float mx = block_reduce(fmaxf(fmaxf(xn0, xn1), fmaxf(xn2, xn3)), red, tid, 1);
    float ex0 = expf(xn0 - mx), ex1 = expf(xn1 - mx), ex2 = expf(xn2 - mx), ex3 = expf(xn3 - mx);
    float esum = block_reduce(ex0 + ex1 + ex2 + ex3, red, tid, 0);
    float inv = 1.0f / esum;

    out[a * 2048 + tid]        = ex0 * inv;
    out[a * 2048 + tid + 512]  = ex1 * inv;
    out[a * 2048 + tid + 1024] = ex2 * inv;
    out[a * 2048 + tid + 1536] = ex3 * inv;
}

// ---------------------------------------------------------------------------
extern "C" void kernel_launch(void* const* d_in, const int* in_sizes, int n_in,
                              void* d_out, int out_size, void* d_ws, size_t ws_size,
                              hipStream_t stream)
{
    const float* signal = (const float*)d_in[0];
    const float* u1     = (const float*)d_in[1];
    const float* u2     = (const float*)d_in[2];
    const float* bilW   = (const float*)d_in[3];
    const float* bilb   = (const float*)d_in[4];
    const float* Wih1   = (const float*)d_in[5];
    // d_in[6] = Whh1 : unused (h0 = 0)
    const float* bih1   = (const float*)d_in[7];
    const float* bhh1   = (const float*)d_in[8];
    const float* Wih2   = (const float*)d_in[9];
    // d_in[10] = Whh2 : unused
    const float* bih2   = (const float*)d_in[11];
    const float* bhh2   = (const float*)d_in[12];
    const float* linW   = (const float*)d_in[13];
    const float* linb   = (const float*)d_in[14];

    float* out = (float*)d_out;
    float* ws  = (float*)d_ws;

    // workspace layout (floats)
    float* B1 = ws;             // 18432   [9][2048]
    float* G  = ws + 18432;     // 55296   [9][6144] (reused for both LSTMs)
    float* B2 = ws + 73728;     // 18432   [9][2048]
    float* B3 = B1;             // reuse (B1 dead after gemv #1)
    float* Z  = ws + 92160;     // 92160   [9][10240]

    k_pre<<<8, 256, 0, stream>>>(signal, u1, bilW, bilb, B1);

    // LSTM 1: gates (i,g,o only) then combine + u2 mask
    k_gemv9<true><<<384, 256, 0, stream>>>(B1, Wih1, bih1, bhh1, G, 6144);
    k_combine<<<72, 256, 0, stream>>>(G, u2, B2);

    // LSTM 2: combine without mask
    k_gemv9<true><<<384, 256, 0, stream>>>(B2, Wih2, bih2, bhh2, G, 6144);
    k_combine<<<72, 256, 0, stream>>>(G, nullptr, B3);

    // Linear: Z[m][n] = h2[m] . linW[n] + linb[n]
    k_gemv9<false><<<640, 256, 0, stream>>>(B3, linW, linb, nullptr, Z, 10240);

    // reshape-sum over 9, instance norm + softmax over 2048
    k_final<<<5, 512, 0, stream>>>(Z, out);
}

// Round 3
// 62.047 us; speedup vs baseline: 1.6417x; 1.6417x over previous
//
#include <hip/hip_runtime.h>
#include <math.h>

#define IOTA_F (1.0f / 137.0f)
#define PHI_F  0.618033988749894f

__device__ __forceinline__ float sigm(float x) { return 1.0f / (1.0f + expf(-x)); }

__device__ __forceinline__ float nan2num(float v) {
    if (isnan(v)) return IOTA_F;
    if (isinf(v)) return v > 0.0f ? 1.0f : IOTA_F;
    return v;
}

// ---------------------------------------------------------------------------
// Kernel 1: instance_norm(5) -> rfft(5) -> re*im -> sigmoid -> softmax(3)
//           -> bilinear(3x3 -> 9) -> mask(u1) -> B1[9][2048]
// ---------------------------------------------------------------------------
__global__ void k_pre(const float* __restrict__ signal,  // [5][2048]
                      const float* __restrict__ u1,      // [9][2048]
                      const float* __restrict__ bilW,    // [9][3][3]
                      const float* __restrict__ bilb,    // [9]
                      float* __restrict__ B1)            // [9][2048]
{
    int s = blockIdx.x * blockDim.x + threadIdx.x;
    if (s >= 2048) return;

    float x0 = signal[0 * 2048 + s];
    float x1 = signal[1 * 2048 + s];
    float x2 = signal[2 * 2048 + s];
    float x3 = signal[3 * 2048 + s];
    float x4 = signal[4 * 2048 + s];

    float mean = (x0 + x1 + x2 + x3 + x4) * 0.2f;
    float d0 = x0 - mean, d1 = x1 - mean, d2 = x2 - mean, d3 = x3 - mean, d4 = x4 - mean;
    float var = (d0 * d0 + d1 * d1 + d2 * d2 + d3 * d3 + d4 * d4) * 0.2f;
    float r = 1.0f / sqrtf(var + 1e-9f);
    d0 *= r; d1 *= r; d2 *= r; d3 *= r; d4 *= r;

    const float c1 = 0.30901699437494742f;   // cos(2pi/5)
    const float c2 = -0.80901699437494745f;  // cos(4pi/5)
    const float s1 = 0.95105651629515357f;   // sin(2pi/5)
    const float s2 = 0.58778525229247314f;   // sin(4pi/5)

    float re1 = d0 + c1 * (d1 + d4) + c2 * (d2 + d3);
    float im1 = -(s1 * (d1 - d4) + s2 * (d2 - d3));
    float re2 = d0 + c2 * (d1 + d4) + c1 * (d2 + d3);
    float im2 = -s2 * (d1 - d4) + s1 * (d2 - d3);

    float p1 = nan2num(re1 * im1);
    float p2 = nan2num(re2 * im2);
    float g0 = 0.5f;                 // k=0: imag == 0 -> sigmoid(0) = 0.5
    float g1 = sigm(p1);
    float g2 = sigm(p2);

    float mx = fmaxf(g0, fmaxf(g1, g2));
    float e0 = expf(g0 - mx), e1 = expf(g1 - mx), e2 = expf(g2 - mx);
    float inv = 1.0f / (e0 + e1 + e2);
    float w[3] = { e0 * inv, e1 * inv, e2 * inv };

    #pragma unroll
    for (int kk = 0; kk < 9; ++kk) {
        float acc = bilb[kk];
        #pragma unroll
        for (int i = 0; i < 3; ++i)
            #pragma unroll
            for (int j = 0; j < 3; ++j)
                acc += w[i] * bilW[kk * 9 + i * 3 + j] * w[j];
        float mask = (u1[kk * 2048 + s] < PHI_F) ? 1.0f : 0.0f;
        B1[kk * 2048 + s] = IOTA_F + acc * mask;
    }
}

// ---------------------------------------------------------------------------
// Kernel 2 (v3): Out[m][jj] = dot(B[m][:], W[row(jj)][:]) + bias1 (+ bias2)
// Block = 256 threads = 4 waves, handles a 16-row tile of W.
//   - wave w owns K-chunk w (512 floats); within a wave, group g (16 lanes)
//     covers rows jj0+g*4 .. jj0+g*4+3 with register-cached B (4x B reuse).
//   - intra-group shfl reduce, then cross-wave reduce via LDS; bias added
//     and final value written here (no partial buffers).
// GATEMAP skips dead f-gate rows: jj in [0,2048) -> phys jj ;
// [2048,6144) -> phys jj + 2048 (g at 4096.., o at 6144..).
// ---------------------------------------------------------------------------
template <bool GATEMAP>
__global__ __launch_bounds__(256) void k_gemv9v3(
    const float* __restrict__ Bv,    // [9][2048]
    const float* __restrict__ W,     // [nrows_phys][2048]
    const float* __restrict__ bias1, // per phys row, or null
    const float* __restrict__ bias2, // per phys row, or null
    float* __restrict__ Out,         // [9][nvrows]
    int nvrows)
{
    __shared__ float lds[4][16][9];

    const int tid  = threadIdx.x;
    const int w    = tid >> 6;        // wave 0..3 = K-chunk
    const int lane = tid & 63;
    const int grp  = lane >> 4;       // 0..3 row-quad within tile
    const int li   = lane & 15;

    const int jj0 = blockIdx.x * 16;
    int jbase = jj0;
    if (GATEMAP && jj0 >= 2048) jbase += 2048;

    const float4* __restrict__ B4 = reinterpret_cast<const float4*>(Bv);
    const float4* __restrict__ W0 =
        reinterpret_cast<const float4*>(W) + ((size_t)jbase + grp * 4) * 512;

    float acc[4][9];
    #pragma unroll
    for (int r = 0; r < 4; ++r)
        #pragma unroll
        for (int m = 0; m < 9; ++m) acc[r][m] = 0.0f;

    const int kb4 = w * 128;          // float4 base of this wave's K chunk

    #pragma unroll 2
    for (int it = 0; it < 8; ++it) {
        const int idx = kb4 + it * 16 + li;
        float4 bv[9];
        #pragma unroll
        for (int m = 0; m < 9; ++m) bv[m] = B4[m * 512 + idx];
        #pragma unroll
        for (int r = 0; r < 4; ++r) {
            float4 wv = W0[(size_t)r * 512 + idx];
            #pragma unroll
            for (int m = 0; m < 9; ++m) {
                acc[r][m] = fmaf(wv.x, bv[m].x, acc[r][m]);
                acc[r][m] = fmaf(wv.y, bv[m].y, acc[r][m]);
                acc[r][m] = fmaf(wv.z, bv[m].z, acc[r][m]);
                acc[r][m] = fmaf(wv.w, bv[m].w, acc[r][m]);
            }
        }
    }

    // reduce within each 16-lane group
    #pragma unroll
    for (int r = 0; r < 4; ++r)
        #pragma unroll
        for (int m = 0; m < 9; ++m) {
            float v = acc[r][m];
            v += __shfl_xor(v, 1);
            v += __shfl_xor(v, 2);
            v += __shfl_xor(v, 4);
            v += __shfl_xor(v, 8);
            acc[r][m] = v;
        }

    if (li == 0) {
        #pragma unroll
        for (int r = 0; r < 4; ++r)
            #pragma unroll
            for (int m = 0; m < 9; ++m)
                lds[w][grp * 4 + r][m] = acc[r][m];
    }
    __syncthreads();

    // cross-wave reduce: 144 threads, one per (row, m)
    if (tid < 144) {
        const int row = tid / 9;
        const int m   = tid - row * 9;
        float v = lds[0][row][m] + lds[1][row][m] + lds[2][row][m] + lds[3][row][m];
        const int jj = jj0 + row;
        int j = jj;
        if (GATEMAP && jj >= 2048) j += 2048;
        if (bias1) v += bias1[j];
        if (bias2) v += bias2[j];
        Out[(size_t)m * nvrows + jj] = v;
    }
}

// ---------------------------------------------------------------------------
// Kernel 3: LSTM nonlinearity + optional mask (bias already in G).
//   h = sigmoid(o) * tanh(sigmoid(i) * tanh(g));  (c0 = 0 -> f gate dead)
// ---------------------------------------------------------------------------
__global__ void k_combine(const float* __restrict__ G,  // [9][6144] (i,g,o)
                          const float* __restrict__ u,  // [9][2048] or nullptr
                          float* __restrict__ Bout)     // [9][2048]
{
    int idx = blockIdx.x * blockDim.x + threadIdx.x;
    if (idx >= 9 * 2048) return;
    int m = idx >> 11;
    int q = idx & 2047;
    const float* Gm = G + (size_t)m * 6144;
    float iv = Gm[q];
    float gv = Gm[2048 + q];
    float ov = Gm[4096 + q];
    float c = sigm(iv) * tanhf(gv);
    float h = sigm(ov) * tanhf(c);
    if (u) h = IOTA_F + h * ((u[idx] < PHI_F) ? 1.0f : 0.0f);
    Bout[idx] = h;
}

// ---------------------------------------------------------------------------
// Kernel 4: per sample a: t[s] = sum_{k=0..8} Z[a*18432 + s*9 + k];
//           instance_norm over s; softmax over s.  (Z includes lin bias.)
// ---------------------------------------------------------------------------
__device__ __forceinline__ float block_reduce(float v, float* red, int tid, int op) {
    #pragma unroll
    for (int off = 32; off > 0; off >>= 1) {
        float o = __shfl_xor(v, off);
        v = op ? fmaxf(v, o) : (v + o);
    }
    __syncthreads();
    if ((tid & 63) == 0) red[tid >> 6] = v;
    __syncthreads();
    float r = red[0];
    #pragma unroll
    for (int w = 1; w < 8; ++w) r = op ? fmaxf(r, red[w]) : (r + red[w]);
    return r;
}

__global__ void k_final(const float* __restrict__ Z,  // [92160] flat
                        float* __restrict__ out)      // [5][2048]
{
    __shared__ float t[2048];
    __shared__ float red[8];
    const int a = blockIdx.x;
    const int tid = threadIdx.x;  // 512 threads

    for (int s = tid; s < 2048; s += 512) {
        const float* zp = Z + a * 18432 + s * 9;
        float acc = 0.0f;
        #pragma unroll
        for (int k = 0; k < 9; ++k) acc += zp[k];
        t[s] = acc;
    }
    __syncthreads();

    float l0 = t[tid], l1 = t[tid + 512], l2 = t[tid + 1024], l3 = t[tid + 1536];

    float ssum = block_reduce(l0 + l1 + l2 + l3, red, tid, 0);
    float mean = ssum * (1.0f / 2048.0f);
    float e0 = l0 - mean, e1 = l1 - mean, e2 = l2 - mean, e3 = l3 - mean;
    float vsum = block_reduce(e0 * e0 + e1 * e1 + e2 * e2 + e3 * e3, red, tid, 0);
    float rstd = 1.0f / sqrtf(vsum * (1.0f / 2048.0f) + 1e-9f);
    float xn0 = e0 * rstd, xn1 = e1 * rstd, xn2 = e2 * rstd, xn3 = e3 * rstd;

    float mx = block_reduce(fmaxf(fmaxf(xn0, xn1), fmaxf(xn2, xn3)), red, tid, 1);
    float ex0 = expf(xn0 - mx), ex1 = expf(xn1 - mx), ex2 = expf(xn2 - mx), ex3 = expf(xn3 - mx);
    float esum = block_reduce(ex0 + ex1 + ex2 + ex3, red, tid, 0);
    float inv = 1.0f / esum;

    out[a * 2048 + tid]        = ex0 * inv;
    out[a * 2048 + tid + 512]  = ex1 * inv;
    out[a * 2048 + tid + 1024] = ex2 * inv;
    out[a * 2048 + tid + 1536] = ex3 * inv;
}

// ---------------------------------------------------------------------------
extern "C" void kernel_launch(void* const* d_in, const int* in_sizes, int n_in,
                              void* d_out, int out_size, void* d_ws, size_t ws_size,
                              hipStream_t stream)
{
    const float* signal = (const float*)d_in[0];
    const float* u1     = (const float*)d_in[1];
    const float* u2     = (const float*)d_in[2];
    const float* bilW   = (const float*)d_in[3];
    const float* bilb   = (const float*)d_in[4];
    const float* Wih1   = (const float*)d_in[5];
    // d_in[6] = Whh1 : unused (h0 = 0)
    const float* bih1   = (const float*)d_in[7];
    const float* bhh1   = (const float*)d_in[8];
    const float* Wih2   = (const float*)d_in[9];
    // d_in[10] = Whh2 : unused
    const float* bih2   = (const float*)d_in[11];
    const float* bhh2   = (const float*)d_in[12];
    const float* linW   = (const float*)d_in[13];
    const float* linb   = (const float*)d_in[14];

    float* out = (float*)d_out;
    float* ws  = (float*)d_ws;

    // workspace layout (floats) — 184320 total = 737 KB (round-1 proven size)
    float* B1 = ws;             // 18432   [9][2048]
    float* G  = ws + 18432;     // 55296   [9][6144] (reused for both LSTMs)
    float* B2 = ws + 73728;     // 18432   [9][2048]
    float* B3 = B1;             // reuse (B1 dead after gemv #1)
    float* Z  = ws + 92160;     // 92160   [9][10240]

    k_pre<<<8, 256, 0, stream>>>(signal, u1, bilW, bilb, B1);

    // LSTM 1: gates (i,g,o only) then combine + u2 mask
    k_gemv9v3<true><<<6144 / 16, 256, 0, stream>>>(B1, Wih1, bih1, bhh1, G, 6144);
    k_combine<<<72, 256, 0, stream>>>(G, u2, B2);

    // LSTM 2
    k_gemv9v3<true><<<6144 / 16, 256, 0, stream>>>(B2, Wih2, bih2, bhh2, G, 6144);
    k_combine<<<72, 256, 0, stream>>>(G, nullptr, B3);

    // Linear: Z[m][n] = h2[m] . linW[n] + linb[n]
    k_gemv9v3<false><<<10240 / 16, 256, 0, stream>>>(B3, linW, linb, nullptr, Z, 10240);

    // reshape-sum over 9, instance norm + softmax over 2048
    k_final<<<5, 512, 0, stream>>>(Z, out);
}

// Round 4
// 56.064 us; speedup vs baseline: 1.8169x; 1.1067x over previous
//
#include <hip/hip_runtime.h>
#include <math.h>

#define IOTA_F (1.0f / 137.0f)
#define PHI_F  0.618033988749894f

__device__ __forceinline__ float sigm(float x) { return 1.0f / (1.0f + expf(-x)); }

__device__ __forceinline__ float nan2num(float v) {
    if (isnan(v)) return IOTA_F;
    if (isinf(v)) return v > 0.0f ? 1.0f : IOTA_F;
    return v;
}

// ---------------------------------------------------------------------------
// Kernel 1: instance_norm(5) -> rfft(5) -> re*im -> sigmoid -> softmax(3)
//           -> bilinear(3x3 -> 9) -> mask(u1) -> B1[9][2048]
// ---------------------------------------------------------------------------
__global__ void k_pre(const float* __restrict__ signal,  // [5][2048]
                      const float* __restrict__ u1,      // [9][2048]
                      const float* __restrict__ bilW,    // [9][3][3]
                      const float* __restrict__ bilb,    // [9]
                      float* __restrict__ B1)            // [9][2048]
{
    int s = blockIdx.x * blockDim.x + threadIdx.x;
    if (s >= 2048) return;

    float x0 = signal[0 * 2048 + s];
    float x1 = signal[1 * 2048 + s];
    float x2 = signal[2 * 2048 + s];
    float x3 = signal[3 * 2048 + s];
    float x4 = signal[4 * 2048 + s];

    float mean = (x0 + x1 + x2 + x3 + x4) * 0.2f;
    float d0 = x0 - mean, d1 = x1 - mean, d2 = x2 - mean, d3 = x3 - mean, d4 = x4 - mean;
    float var = (d0 * d0 + d1 * d1 + d2 * d2 + d3 * d3 + d4 * d4) * 0.2f;
    float r = 1.0f / sqrtf(var + 1e-9f);
    d0 *= r; d1 *= r; d2 *= r; d3 *= r; d4 *= r;

    const float c1 = 0.30901699437494742f;   // cos(2pi/5)
    const float c2 = -0.80901699437494745f;  // cos(4pi/5)
    const float s1 = 0.95105651629515357f;   // sin(2pi/5)
    const float s2 = 0.58778525229247314f;   // sin(4pi/5)

    float re1 = d0 + c1 * (d1 + d4) + c2 * (d2 + d3);
    float im1 = -(s1 * (d1 - d4) + s2 * (d2 - d3));
    float re2 = d0 + c2 * (d1 + d4) + c1 * (d2 + d3);
    float im2 = -s2 * (d1 - d4) + s1 * (d2 - d3);

    float p1 = nan2num(re1 * im1);
    float p2 = nan2num(re2 * im2);
    float g0 = 0.5f;                 // k=0: imag == 0 -> sigmoid(0) = 0.5
    float g1 = sigm(p1);
    float g2 = sigm(p2);

    float mx = fmaxf(g0, fmaxf(g1, g2));
    float e0 = expf(g0 - mx), e1 = expf(g1 - mx), e2 = expf(g2 - mx);
    float inv = 1.0f / (e0 + e1 + e2);
    float w[3] = { e0 * inv, e1 * inv, e2 * inv };

    #pragma unroll
    for (int kk = 0; kk < 9; ++kk) {
        float acc = bilb[kk];
        #pragma unroll
        for (int i = 0; i < 3; ++i)
            #pragma unroll
            for (int j = 0; j < 3; ++j)
                acc += w[i] * bilW[kk * 9 + i * 3 + j] * w[j];
        float mask = (u1[kk * 2048 + s] < PHI_F) ? 1.0f : 0.0f;
        B1[kk * 2048 + s] = IOTA_F + acc * mask;
    }
}

// ---------------------------------------------------------------------------
// Kernel 2: fused LSTM layer (gemv + nonlinearity).
// Block = 256 threads = 4 waves; block covers 4 q-columns (grid 512 = 2/CU).
//   wave w owns K-chunk w (512 floats); group g (16 lanes) owns q = q0+g and
//   its THREE live gate rows {q, 4096+q, 6144+q} (i,g,o; f dead since c0=0).
//   After shfl+LDS reduce, epilogue computes
//     h = sigmoid(o) * tanh(sigmoid(i) * tanh(g))  (+ optional u-mask)
//   and writes Bout[m][q] directly — no intermediate G buffer.
// ---------------------------------------------------------------------------
template <bool MASK>
__global__ __launch_bounds__(256) void k_lstm_fused(
    const float* __restrict__ Bv,   // [9][2048]
    const float* __restrict__ W,    // [8192][2048]
    const float* __restrict__ b1,   // [8192]
    const float* __restrict__ b2,   // [8192]
    const float* __restrict__ u,    // [9][2048] or null
    float* __restrict__ Bout)       // [9][2048]
{
    __shared__ float lds[4][4][3][9];

    const int tid  = threadIdx.x;
    const int w    = tid >> 6;      // wave = K-chunk
    const int lane = tid & 63;
    const int grp  = lane >> 4;     // q within block
    const int li   = lane & 15;

    const int q = blockIdx.x * 4 + grp;

    const float4* __restrict__ B4 = reinterpret_cast<const float4*>(Bv);
    const float4* __restrict__ Wi = reinterpret_cast<const float4*>(W) + (size_t)q * 512;
    const float4* __restrict__ Wg = Wi + (size_t)4096 * 512;
    const float4* __restrict__ Wo = Wi + (size_t)6144 * 512;

    float acc[3][9];
    #pragma unroll
    for (int r = 0; r < 3; ++r)
        #pragma unroll
        for (int m = 0; m < 9; ++m) acc[r][m] = 0.0f;

    const int kb4 = w * 128;

    #pragma unroll 2
    for (int it = 0; it < 8; ++it) {
        const int idx = kb4 + it * 16 + li;
        float4 bv[9];
        #pragma unroll
        for (int m = 0; m < 9; ++m) bv[m] = B4[m * 512 + idx];
        float4 wv0 = Wi[idx];
        float4 wv1 = Wg[idx];
        float4 wv2 = Wo[idx];
        #pragma unroll
        for (int m = 0; m < 9; ++m) {
            acc[0][m] = fmaf(wv0.x, bv[m].x, acc[0][m]);
            acc[0][m] = fmaf(wv0.y, bv[m].y, acc[0][m]);
            acc[0][m] = fmaf(wv0.z, bv[m].z, acc[0][m]);
            acc[0][m] = fmaf(wv0.w, bv[m].w, acc[0][m]);
            acc[1][m] = fmaf(wv1.x, bv[m].x, acc[1][m]);
            acc[1][m] = fmaf(wv1.y, bv[m].y, acc[1][m]);
            acc[1][m] = fmaf(wv1.z, bv[m].z, acc[1][m]);
            acc[1][m] = fmaf(wv1.w, bv[m].w, acc[1][m]);
            acc[2][m] = fmaf(wv2.x, bv[m].x, acc[2][m]);
            acc[2][m] = fmaf(wv2.y, bv[m].y, acc[2][m]);
            acc[2][m] = fmaf(wv2.z, bv[m].z, acc[2][m]);
            acc[2][m] = fmaf(wv2.w, bv[m].w, acc[2][m]);
        }
    }

    #pragma unroll
    for (int r = 0; r < 3; ++r)
        #pragma unroll
        for (int m = 0; m < 9; ++m) {
            float v = acc[r][m];
            v += __shfl_xor(v, 1);
            v += __shfl_xor(v, 2);
            v += __shfl_xor(v, 4);
            v += __shfl_xor(v, 8);
            acc[r][m] = v;
        }

    if (li == 0) {
        #pragma unroll
        for (int r = 0; r < 3; ++r)
            #pragma unroll
            for (int m = 0; m < 9; ++m)
                lds[w][grp][r][m] = acc[r][m];
    }
    __syncthreads();

    if (tid < 36) {
        const int qq = tid / 9;
        const int m  = tid - qq * 9;
        const int qg = blockIdx.x * 4 + qq;
        float iv = lds[0][qq][0][m] + lds[1][qq][0][m] + lds[2][qq][0][m] + lds[3][qq][0][m];
        float gv = lds[0][qq][1][m] + lds[1][qq][1][m] + lds[2][qq][1][m] + lds[3][qq][1][m];
        float ov = lds[0][qq][2][m] + lds[1][qq][2][m] + lds[2][qq][2][m] + lds[3][qq][2][m];
        iv += b1[qg] + b2[qg];
        gv += b1[4096 + qg] + b2[4096 + qg];
        ov += b1[6144 + qg] + b2[6144 + qg];
        float c = sigm(iv) * tanhf(gv);
        float h = sigm(ov) * tanhf(c);
        if (MASK) h = IOTA_F + h * ((u[m * 2048 + qg] < PHI_F) ? 1.0f : 0.0f);
        Bout[m * 2048 + qg] = h;
    }
}

// ---------------------------------------------------------------------------
// Kernel 3: linear gemv. Block = 4 waves, 4*R rows (grid 512 = 2/CU, R=5).
//   wave w = K-chunk; group g handles rows row0+g*R .. +R-1 with
//   register-cached B. LDS cross-wave reduce; bias added; writes Z.
// ---------------------------------------------------------------------------
template <int R>
__global__ __launch_bounds__(256) void k_gemvR(
    const float* __restrict__ Bv,    // [9][2048]
    const float* __restrict__ W,     // [nrows][2048]
    const float* __restrict__ bias,  // [nrows]
    float* __restrict__ Out,         // [9][nrows]
    int nrows)
{
    __shared__ float lds[4][4 * R][9];

    const int tid  = threadIdx.x;
    const int w    = tid >> 6;
    const int lane = tid & 63;
    const int grp  = lane >> 4;
    const int li   = lane & 15;

    const int rowB = blockIdx.x * 4 * R;           // block's first row
    const int row0 = rowB + grp * R;               // group's first row

    const float4* __restrict__ B4 = reinterpret_cast<const float4*>(Bv);
    const float4* __restrict__ W0 = reinterpret_cast<const float4*>(W) + (size_t)row0 * 512;

    float acc[R][9];
    #pragma unroll
    for (int r = 0; r < R; ++r)
        #pragma unroll
        for (int m = 0; m < 9; ++m) acc[r][m] = 0.0f;

    const int kb4 = w * 128;

    #pragma unroll 2
    for (int it = 0; it < 8; ++it) {
        const int idx = kb4 + it * 16 + li;
        float4 bv[9];
        #pragma unroll
        for (int m = 0; m < 9; ++m) bv[m] = B4[m * 512 + idx];
        #pragma unroll
        for (int r = 0; r < R; ++r) {
            float4 wv = W0[(size_t)r * 512 + idx];
            #pragma unroll
            for (int m = 0; m < 9; ++m) {
                acc[r][m] = fmaf(wv.x, bv[m].x, acc[r][m]);
                acc[r][m] = fmaf(wv.y, bv[m].y, acc[r][m]);
                acc[r][m] = fmaf(wv.z, bv[m].z, acc[r][m]);
                acc[r][m] = fmaf(wv.w, bv[m].w, acc[r][m]);
            }
        }
    }

    #pragma unroll
    for (int r = 0; r < R; ++r)
        #pragma unroll
        for (int m = 0; m < 9; ++m) {
            float v = acc[r][m];
            v += __shfl_xor(v, 1);
            v += __shfl_xor(v, 2);
            v += __shfl_xor(v, 4);
            v += __shfl_xor(v, 8);
            acc[r][m] = v;
        }

    if (li == 0) {
        #pragma unroll
        for (int r = 0; r < R; ++r)
            #pragma unroll
            for (int m = 0; m < 9; ++m)
                lds[w][grp * R + r][m] = acc[r][m];
    }
    __syncthreads();

    for (int t = tid; t < 4 * R * 9; t += 256) {
        const int row = t / 9;
        const int m   = t - row * 9;
        float v = lds[0][row][m] + lds[1][row][m] + lds[2][row][m] + lds[3][row][m];
        const int grow = rowB + row;
        Out[(size_t)m * nrows + grow] = v + bias[grow];
    }
}

// ---------------------------------------------------------------------------
// Kernel 4: per sample a: t[s] = sum_{k=0..8} Z[a*18432 + s*9 + k];
//           instance_norm over s; softmax over s.  (Z includes lin bias.)
// ---------------------------------------------------------------------------
__device__ __forceinline__ float block_reduce(float v, float* red, int tid, int op) {
    #pragma unroll
    for (int off = 32; off > 0; off >>= 1) {
        float o = __shfl_xor(v, off);
        v = op ? fmaxf(v, o) : (v + o);
    }
    __syncthreads();
    if ((tid & 63) == 0) red[tid >> 6] = v;
    __syncthreads();
    float r = red[0];
    #pragma unroll
    for (int w = 1; w < 8; ++w) r = op ? fmaxf(r, red[w]) : (r + red[w]);
    return r;
}

__global__ void k_final(const float* __restrict__ Z,  // [92160] flat
                        float* __restrict__ out)      // [5][2048]
{
    __shared__ float t[2048];
    __shared__ float red[8];
    const int a = blockIdx.x;
    const int tid = threadIdx.x;  // 512 threads

    for (int s = tid; s < 2048; s += 512) {
        const float* zp = Z + a * 18432 + s * 9;
        float acc = 0.0f;
        #pragma unroll
        for (int k = 0; k < 9; ++k) acc += zp[k];
        t[s] = acc;
    }
    __syncthreads();

    float l0 = t[tid], l1 = t[tid + 512], l2 = t[tid + 1024], l3 = t[tid + 1536];

    float ssum = block_reduce(l0 + l1 + l2 + l3, red, tid, 0);
    float mean = ssum * (1.0f / 2048.0f);
    float e0 = l0 - mean, e1 = l1 - mean, e2 = l2 - mean, e3 = l3 - mean;
    float vsum = block_reduce(e0 * e0 + e1 * e1 + e2 * e2 + e3 * e3, red, tid, 0);
    float rstd = 1.0f / sqrtf(vsum * (1.0f / 2048.0f) + 1e-9f);
    float xn0 = e0 * rstd, xn1 = e1 * rstd, xn2 = e2 * rstd, xn3 = e3 * rstd;

    float mx = block_reduce(fmaxf(fmaxf(xn0, xn1), fmaxf(xn2, xn3)), red, tid, 1);
    float ex0 = expf(xn0 - mx), ex1 = expf(xn1 - mx), ex2 = expf(xn2 - mx), ex3 = expf(xn3 - mx);
    float esum = block_reduce(ex0 + ex1 + ex2 + ex3, red, tid, 0);
    float inv = 1.0f / esum;

    out[a * 2048 + tid]        = ex0 * inv;
    out[a * 2048 + tid + 512]  = ex1 * inv;
    out[a * 2048 + tid + 1024] = ex2 * inv;
    out[a * 2048 + tid + 1536] = ex3 * inv;
}

// ---------------------------------------------------------------------------
extern "C" void kernel_launch(void* const* d_in, const int* in_sizes, int n_in,
                              void* d_out, int out_size, void* d_ws, size_t ws_size,
                              hipStream_t stream)
{
    const float* signal = (const float*)d_in[0];
    const float* u1     = (const float*)d_in[1];
    const float* u2     = (const float*)d_in[2];
    const float* bilW   = (const float*)d_in[3];
    const float* bilb   = (const float*)d_in[4];
    const float* Wih1   = (const float*)d_in[5];
    // d_in[6] = Whh1 : unused (h0 = 0)
    const float* bih1   = (const float*)d_in[7];
    const float* bhh1   = (const float*)d_in[8];
    const float* Wih2   = (const float*)d_in[9];
    // d_in[10] = Whh2 : unused
    const float* bih2   = (const float*)d_in[11];
    const float* bhh2   = (const float*)d_in[12];
    const float* linW   = (const float*)d_in[13];
    const float* linb   = (const float*)d_in[14];

    float* out = (float*)d_out;
    float* ws  = (float*)d_ws;

    // workspace layout (floats): B1[18432] B2[18432] Z[92160]  (~516 KB)
    float* B1 = ws;
    float* B2 = ws + 18432;
    float* B3 = B1;             // reuse (B1 dead after LSTM 1)
    float* Z  = ws + 36864;

    k_pre<<<8, 256, 0, stream>>>(signal, u1, bilW, bilb, B1);

    // LSTM layers: gemv + nonlinearity fused, grid 512 = exactly 2 blocks/CU
    k_lstm_fused<true><<<512, 256, 0, stream>>>(B1, Wih1, bih1, bhh1, u2, B2);
    k_lstm_fused<false><<<512, 256, 0, stream>>>(B2, Wih2, bih2, bhh2, nullptr, B3);

    // Linear: 10240 rows, 20 rows/block -> 512 blocks = 2/CU
    k_gemvR<5><<<512, 256, 0, stream>>>(B3, linW, linb, Z, 10240);

    // reshape-sum over 9, instance norm + softmax over 2048
    k_final<<<5, 512, 0, stream>>>(Z, out);
}